// Round 1
// baseline (1504.324 us; speedup 1.0000x reference)
//
#include <hip/hip_runtime.h>
#include <cstdint>

#define NTOT 242991
#define BATCH 8
#define KTOT 8741           // 2000*4 + 741
#define CAP 8192            // candidate buffer per (b,level)
#define NBIN 8192           // score histogram bins (top 13 ord bits)

// level geometry: offsets/sizes for A*h*w per level
__device__ __forceinline__ void locate(int n, int& l, int& H, int& W, int& loc) {
    if (n < 182400)      { l = 0; H = 200; W = 304; loc = n; }
    else if (n < 228000) { l = 1; H = 100; W = 152; loc = n - 182400; }
    else if (n < 239400) { l = 2; H = 50;  W = 76;  loc = n - 228000; }
    else if (n < 242250) { l = 3; H = 25;  W = 38;  loc = n - 239400; }
    else                 { l = 4; H = 13;  W = 19;  loc = n - 242250; }
}

__device__ __forceinline__ int level_of(int n) {
    if (n < 182400) return 0;
    if (n < 228000) return 1;
    if (n < 239400) return 2;
    if (n < 242250) return 3;
    return 4;
}

// ---- kernel 0: zero hist + counters + output ----
__global__ void k_zero(uint32_t* meta, int meta_n, float* out, int out_n) {
    int i = blockIdx.x * blockDim.x + threadIdx.x;
    if (i < meta_n) meta[i] = 0u;
    if (i < out_n) out[i] = 0.0f;
}

// ---- kernel 1: scores -> ordered keys + per-(b,level) histogram ----
__global__ void k_score(const float* __restrict__ c0, const float* __restrict__ c1,
                        const float* __restrict__ c2, const float* __restrict__ c3,
                        const float* __restrict__ c4,
                        uint32_t* __restrict__ keys32, uint32_t* __restrict__ hist) {
    int gid = blockIdx.x * blockDim.x + threadIdx.x;
    if (gid >= BATCH * NTOT) return;
    int b = gid / NTOT, n = gid - b * NTOT;
    int l, H, W, loc; locate(n, l, H, W, loc);
    int a = loc % 3, hw = loc / 3;
    int w = hw % W, h = hw / W;
    const float* cp = (l == 0) ? c0 : (l == 1) ? c1 : (l == 2) ? c2 : (l == 3) ? c3 : c4;
    float s = cp[((b * 3 + a) * H + h) * W + w];
    uint32_t u = __float_as_uint(s);
    u ^= (u >> 31) ? 0xFFFFFFFFu : 0x80000000u;   // monotonic float->uint
    keys32[gid] = u;
    atomicAdd(&hist[(b * 5 + l) * NBIN + (u >> 19)], 1u);
}

// ---- kernel 2: per-(b,level) find threshold bin + remainder r ----
__global__ void k_bins(const uint32_t* __restrict__ hist, int* __restrict__ binT,
                       int* __restrict__ rrem) {
    int bl = blockIdx.x;             // 40 blocks
    const uint32_t* h = hist + bl * NBIN;
    int l = bl % 5;
    uint32_t k = (l == 4) ? 741u : 2000u;
    __shared__ uint32_t tsum[256];
    __shared__ uint32_t cft[256];
    int t = threadIdx.x;             // 256 threads
    uint32_t s = 0;
    for (int i = 0; i < 32; i++) s += h[t * 32 + i];
    tsum[t] = s;
    __syncthreads();
    if (t == 0) {
        uint32_t c = 0;
        for (int q = 255; q >= 0; q--) { cft[q] = c; c += tsum[q]; }
    }
    __syncthreads();
    if (cft[t] < k && cft[t] + tsum[t] >= k) {
        uint32_t cum = cft[t];
        for (int bin = t * 32 + 31; bin >= t * 32; bin--) {
            uint32_t hh = h[bin];
            if (cum + hh >= k) { binT[bl] = bin; rrem[bl] = (int)(k - cum); break; }
            cum += hh;
        }
    }
}

// ---- kernel 3: compact definite keeps + threshold-bin candidates ----
__global__ void k_compact(const uint32_t* __restrict__ keys32, const int* __restrict__ binT,
                          uint32_t* __restrict__ keep, uint32_t* __restrict__ keep_cnt,
                          uint32_t* __restrict__ cand, uint32_t* __restrict__ cand_cnt) {
    int gid = blockIdx.x * blockDim.x + threadIdx.x;
    if (gid >= BATCH * NTOT) return;
    int b = gid / NTOT, n = gid - b * NTOT;
    int l = level_of(n);
    uint32_t u = keys32[gid];
    int bin = (int)(u >> 19);
    int T = binT[b * 5 + l];
    if (bin > T) {
        uint32_t p = atomicAdd(&keep_cnt[b], 1u);
        keep[b * KTOT + p] = (uint32_t)n;
    } else if (bin == T) {
        uint32_t p = atomicAdd(&cand_cnt[b * 5 + l], 1u);
        if (p < CAP) cand[(b * 5 + l) * CAP + p] = (uint32_t)n;
    }
}

// ---- kernel 4: exact radix select over candidates, append top-r ----
__global__ void k_select(const uint32_t* __restrict__ keys32, const uint32_t* __restrict__ cand,
                         const uint32_t* __restrict__ cand_cnt, const int* __restrict__ rrem,
                         uint32_t* __restrict__ keep, uint32_t* __restrict__ keep_cnt) {
    int bl = blockIdx.x;             // 40 blocks
    int b = bl / 5;
    int C = (int)min(cand_cnt[bl], (uint32_t)CAP);
    int r = rrem[bl];
    const uint32_t* cd = cand + bl * CAP;
    __shared__ uint32_t sh_hist[256];
    __shared__ unsigned long long pref_sh;
    __shared__ int kk_sh;
    int t = threadIdx.x;             // 256 threads
    if (t == 0) { pref_sh = 0ull; kk_sh = r; }
    __syncthreads();
    for (int shift = 56; shift >= 0; shift -= 8) {
        sh_hist[t] = 0u;
        __syncthreads();
        unsigned long long pref = pref_sh;
        for (int i = t; i < C; i += 256) {
            uint32_t n = cd[i];
            unsigned long long key =
                ((unsigned long long)keys32[b * NTOT + n] << 32) | (uint32_t)(~n);
            bool match = (shift == 56) || ((key >> (shift + 8)) == (pref >> (shift + 8)));
            if (match) atomicAdd(&sh_hist[(uint32_t)(key >> shift) & 255u], 1u);
        }
        __syncthreads();
        if (t == 0) {
            int kk = kk_sh; uint32_t cum = 0;
            for (int d = 255; d >= 0; d--) {
                uint32_t hh = sh_hist[d];
                if (cum + hh >= (uint32_t)kk) {
                    pref_sh = pref | ((unsigned long long)d << shift);
                    kk_sh = kk - (int)cum;
                    break;
                }
                cum += hh;
            }
        }
        __syncthreads();
    }
    unsigned long long Tk = pref_sh;
    for (int i = t; i < C; i += 256) {
        uint32_t n = cd[i];
        unsigned long long key =
            ((unsigned long long)keys32[b * NTOT + n] << 32) | (uint32_t)(~n);
        if (key >= Tk) {
            uint32_t p = atomicAdd(&keep_cnt[b], 1u);
            keep[b * KTOT + p] = n;
        }
    }
}

// ---- kernel 5: decode + clip + validity for kept anchors ----
__global__ void k_decode(const float* __restrict__ b0, const float* __restrict__ b1,
                         const float* __restrict__ b2, const float* __restrict__ b3,
                         const float* __restrict__ b4, const float* __restrict__ anchors,
                         const uint32_t* __restrict__ keys32, const uint32_t* __restrict__ keep,
                         float4* __restrict__ nbox, unsigned long long* __restrict__ nkey,
                         float* __restrict__ nscore) {
    int gid = blockIdx.x * blockDim.x + threadIdx.x;
    if (gid >= BATCH * KTOT) return;
    int b = gid / KTOT;
    int n = (int)keep[gid];
    int l, H, W, loc; locate(n, l, H, W, loc);
    int a = loc % 3, hw = loc / 3;
    int w = hw % W, h = hw / W;
    const float* bp = (l == 0) ? b0 : (l == 1) ? b1 : (l == 2) ? b2 : (l == 3) ? b3 : b4;
    int HW = H * W;
    int base = ((b * 12 + a * 4) * H + h) * W + w;
    float dx = bp[base], dy = bp[base + HW];
    float dw = bp[base + 2 * HW], dh = bp[base + 3 * HW];
    float ax1 = anchors[4 * n], ay1 = anchors[4 * n + 1];
    float ax2 = anchors[4 * n + 2], ay2 = anchors[4 * n + 3];
    float wa = ax2 - ax1, ha = ay2 - ay1;
    float cxa = ax1 + 0.5f * wa, cya = ay1 + 0.5f * ha;
    const float CLIPV = 4.135166556742356f;    // log(1000/16)
    dw = fminf(dw, CLIPV); dh = fminf(dh, CLIPV);
    float cx = dx * wa + cxa, cy = dy * ha + cya;
    float pw = expf(dw) * wa, ph = expf(dh) * ha;
    float x1 = cx - 0.5f * pw, y1 = cy - 0.5f * ph;
    float x2 = cx + 0.5f * pw, y2 = cy + 0.5f * ph;
    x1 = fminf(fmaxf(x1, 0.f), 1216.f); x2 = fminf(fmaxf(x2, 0.f), 1216.f);
    y1 = fminf(fmaxf(y1, 0.f), 800.f);  y2 = fminf(fmaxf(y2, 0.f), 800.f);
    bool valid = ((x2 - x1) >= 1e-3f) && ((y2 - y1) >= 1e-3f);
    uint32_t o = keys32[b * NTOT + n];
    uint32_t sb = (o & 0x80000000u) ? (o ^ 0x80000000u) : ~o;
    float score = __uint_as_float(sb);
    float off = (float)l * 1217.0f;            // max(H,W)+1
    nbox[gid] = make_float4(x1 + off, y1 + off, x2 + off, y2 + off);
    nkey[gid] = valid ? (((unsigned long long)o << 32) | (uint32_t)(~n)) : 0ull;
    nscore[gid] = score;
}

// ---- kernel 6: greedy batched NMS, one block per batch image ----
__launch_bounds__(1024)
__global__ void k_nms(const float4* __restrict__ nbox, const unsigned long long* __restrict__ nkey,
                      const float* __restrict__ nscore, float* __restrict__ out) {
    int b = blockIdx.x, t = threadIdx.x;
    float4 bx[9]; unsigned long long key[9]; float sc[9];
#pragma unroll
    for (int i = 0; i < 9; i++) {
        int j = t + i * 1024;
        if (j < KTOT) {
            bx[i] = nbox[b * KTOT + j];
            key[i] = nkey[b * KTOT + j];
            sc[i] = nscore[b * KTOT + j];
        } else {
            bx[i] = make_float4(0.f, 0.f, 0.f, 0.f);
            key[i] = 0ull; sc[i] = 0.f;
        }
    }
    __shared__ unsigned long long wred[16];
    __shared__ unsigned long long gk_sh;
    __shared__ float pick[5];
    int lane = t & 63, wid = t >> 6;
    for (int it = 0; it < 100; it++) {
        unsigned long long lm = 0ull;
#pragma unroll
        for (int i = 0; i < 9; i++) lm = (key[i] > lm) ? key[i] : lm;
#pragma unroll
        for (int o = 32; o > 0; o >>= 1) {
            unsigned long long other = __shfl_down(lm, o, 64);
            lm = (other > lm) ? other : lm;
        }
        if (lane == 0) wred[wid] = lm;
        __syncthreads();
        if (t == 0) {
            unsigned long long m = wred[0];
            for (int q = 1; q < 16; q++) m = (wred[q] > m) ? wred[q] : m;
            gk_sh = m;
        }
        __syncthreads();
        unsigned long long g = gk_sh;
        if (g == 0ull) break;   // uniform
#pragma unroll
        for (int i = 0; i < 9; i++) {
            if (key[i] == g) {  // unique owner (keys contain unique anchor idx)
                uint32_t n = ~(uint32_t)(g & 0xFFFFFFFFull);
                float off = (float)level_of((int)n) * 1217.0f;
                float* ob = out + ((size_t)b * 100 + it) * 4;
                ob[0] = bx[i].x - off; ob[1] = bx[i].y - off;
                ob[2] = bx[i].z - off; ob[3] = bx[i].w - off;
                out[3200 + b * 100 + it] = sc[i];
                pick[0] = bx[i].x; pick[1] = bx[i].y;
                pick[2] = bx[i].z; pick[3] = bx[i].w;
                pick[4] = (bx[i].z - bx[i].x) * (bx[i].w - bx[i].y);
                key[i] = 0ull;  // suppress self
            }
        }
        __syncthreads();
        float px1 = pick[0], py1 = pick[1], px2 = pick[2], py2 = pick[3], pa = pick[4];
#pragma unroll
        for (int i = 0; i < 9; i++) {
            if (key[i] != 0ull) {
                float xx1 = fmaxf(bx[i].x, px1), yy1 = fmaxf(bx[i].y, py1);
                float xx2 = fminf(bx[i].z, px2), yy2 = fminf(bx[i].w, py2);
                float inter = fmaxf(xx2 - xx1, 0.f) * fmaxf(yy2 - yy1, 0.f);
                float aj = (bx[i].z - bx[i].x) * (bx[i].w - bx[i].y);
                float un = aj + pa - inter;
                float iou = (un > 0.f) ? (inter / un) : 0.f;
                if (iou > 0.7f) key[i] = 0ull;
            }
        }
        __syncthreads();
    }
}

extern "C" void kernel_launch(void* const* d_in, const int* in_sizes, int n_in,
                              void* d_out, int out_size, void* d_ws, size_t ws_size,
                              hipStream_t stream) {
    // setup_inputs() dict order: cls0, box0, cls1, box1, cls2, box2, cls3, box3, cls4, box4, anchors
    const float* cls[5] = { (const float*)d_in[0], (const float*)d_in[2], (const float*)d_in[4],
                            (const float*)d_in[6], (const float*)d_in[8] };
    const float* box[5] = { (const float*)d_in[1], (const float*)d_in[3], (const float*)d_in[5],
                            (const float*)d_in[7], (const float*)d_in[9] };
    const float* anchors = (const float*)d_in[10];
    float* out = (float*)d_out;

    // workspace layout (all aligned: counts below are multiples keeping 16B alignment)
    uint32_t* keys32   = (uint32_t*)d_ws;                      // B*NTOT
    uint32_t* hist     = keys32 + (size_t)BATCH * NTOT;        // 40*NBIN
    int*      binT     = (int*)(hist + 40 * NBIN);             // 40
    int*      rrem     = binT + 40;                            // 40
    uint32_t* keep_cnt = (uint32_t*)(rrem + 40);               // 8
    uint32_t* cand_cnt = keep_cnt + 8;                         // 40
    uint32_t* keep     = cand_cnt + 40;                        // B*KTOT = 69928
    uint32_t* cand     = keep + (size_t)BATCH * KTOT;          // 40*CAP
    // pad so float4 array is 16B aligned: current u32 count = B*NTOT + 40*NBIN + 128 + B*KTOT + 40*CAP
    size_t u32s = (size_t)BATCH * NTOT + 40 * NBIN + 128 + (size_t)BATCH * KTOT + 40 * CAP;
    u32s = (u32s + 3) & ~(size_t)3;
    float4* nbox = (float4*)((uint32_t*)d_ws + u32s);          // B*KTOT float4
    unsigned long long* nkey = (unsigned long long*)(nbox + (size_t)BATCH * KTOT);
    float* nscore = (float*)(nkey + (size_t)BATCH * KTOT);

    int meta_n = 40 * NBIN + 40 + 40 + 8 + 40;                 // hist..cand_cnt contiguous
    {
        int tot = meta_n > out_size ? meta_n : out_size;
        k_zero<<<(tot + 255) / 256, 256, 0, stream>>>(hist, meta_n, out, out_size);
    }
    {
        int tot = BATCH * NTOT;
        k_score<<<(tot + 255) / 256, 256, 0, stream>>>(cls[0], cls[1], cls[2], cls[3], cls[4],
                                                       keys32, hist);
    }
    k_bins<<<40, 256, 0, stream>>>(hist, binT, rrem);
    {
        int tot = BATCH * NTOT;
        k_compact<<<(tot + 255) / 256, 256, 0, stream>>>(keys32, binT, keep, keep_cnt,
                                                         cand, cand_cnt);
    }
    k_select<<<40, 256, 0, stream>>>(keys32, cand, cand_cnt, rrem, keep, keep_cnt);
    {
        int tot = BATCH * KTOT;
        k_decode<<<(tot + 255) / 256, 256, 0, stream>>>(box[0], box[1], box[2], box[3], box[4],
                                                        anchors, keys32, keep, nbox, nkey, nscore);
    }
    k_nms<<<BATCH, 1024, 0, stream>>>(nbox, nkey, nscore, out);
}

// Round 2
// 622.242 us; speedup vs baseline: 2.4176x; 2.4176x over previous
//
#include <hip/hip_runtime.h>
#include <cstdint>

#define NTOT 242991
#define BATCH 8
#define KTOT 8741           // 2000*4 + 741
#define CAP 8192            // candidate buffer per (b,level)
#define NBIN 4096           // LDS histogram bins (top 12 ordered bits)
#define NREP 2              // replicated LDS histograms

__device__ __forceinline__ int level_of(int n) {
    if (n < 182400) return 0;
    if (n < 228000) return 1;
    if (n < 239400) return 2;
    if (n < 242250) return 3;
    return 4;
}

__device__ __forceinline__ void locate(int n, int& l, int& H, int& W, int& loc) {
    if (n < 182400)      { l = 0; H = 200; W = 304; loc = n; }
    else if (n < 228000) { l = 1; H = 100; W = 152; loc = n - 182400; }
    else if (n < 239400) { l = 2; H = 50;  W = 76;  loc = n - 228000; }
    else if (n < 242250) { l = 3; H = 25;  W = 38;  loc = n - 239400; }
    else                 { l = 4; H = 13;  W = 19;  loc = n - 242250; }
}

// ---- kernel 0: zero counters + output ----
__global__ void k_zero(uint32_t* cnts, float* out, int out_n) {
    int i = blockIdx.x * blockDim.x + threadIdx.x;
    if (i < 80) cnts[i] = 0u;           // keep_cnt[40] + cand_cnt[40]
    if (i < out_n) out[i] = 0.0f;
}

// ---- kernel 1: per-(b,level) score keys + LDS hist + threshold + compact ----
// one block per (b,level); 40 blocks x 1024 threads
__global__ __launch_bounds__(1024)
void k_topk(const float* __restrict__ c0, const float* __restrict__ c1,
            const float* __restrict__ c2, const float* __restrict__ c3,
            const float* __restrict__ c4,
            uint32_t* __restrict__ keys32,
            uint32_t* __restrict__ keep, uint32_t* __restrict__ keep_cnt,
            uint32_t* __restrict__ cand, uint32_t* __restrict__ cand_cnt,
            int* __restrict__ binT, int* __restrict__ rrem) {
    const int segs[5] = {182400, 45600, 11400, 2850, 741};
    const int offs[5] = {0, 182400, 228000, 239400, 242250};
    const int HWs[5]  = {60800, 15200, 3800, 950, 247};
    const int kls[5]  = {2000, 2000, 2000, 2000, 741};
    int bl = blockIdx.x, b = bl / 5, l = bl % 5;
    int seg = segs[l], off = offs[l], HW = HWs[l];
    uint32_t k = (uint32_t)kls[l];
    const float* cp = (l == 0) ? c0 : (l == 1) ? c1 : (l == 2) ? c2 : (l == 3) ? c3 : c4;
    const float* base = cp + (size_t)b * 3 * HW;   // contiguous [a][h][w] block
    int t = threadIdx.x;

    __shared__ uint32_t hist[NREP][NBIN];   // 32 KB
    __shared__ uint32_t tsum[1024];
    __shared__ uint32_t sbuf[1024];
    __shared__ int T_sh;

    for (int j = t; j < NREP * NBIN; j += 1024) ((uint32_t*)hist)[j] = 0u;
    __syncthreads();

    // phase 1: read scores (contiguous), write ordered keys (anchor order), LDS hist
    int rep = (t >> 6) & (NREP - 1);
    for (int i = t; i < seg; i += 1024) {
        float s = base[i];
        uint32_t u = __float_as_uint(s);
        u ^= (u >> 31) ? 0xFFFFFFFFu : 0x80000000u;   // monotonic float->uint
        int a = i / HW, r = i - a * HW;               // mem idx -> anchor idx
        keys32[(size_t)b * NTOT + off + r * 3 + a] = u;
        atomicAdd(&hist[rep][u >> 20], 1u);
    }
    __syncthreads();

    // phase 2: merge replicas + group-of-4 sums
    uint32_t gs = 0;
#pragma unroll
    for (int q = 0; q < 4; q++) {
        int bin = t * 4 + q;
        uint32_t v = hist[0][bin];
#pragma unroll
        for (int rp = 1; rp < NREP; rp++) v += hist[rp][bin];
        hist[0][bin] = v;
        gs += v;
    }
    tsum[t] = gs; sbuf[t] = gs;
    __syncthreads();
    // inclusive suffix scan (Hillis-Steele)
    for (int d = 1; d < 1024; d <<= 1) {
        uint32_t add = (t + d < 1024) ? sbuf[t + d] : 0u;
        __syncthreads();
        sbuf[t] += add;
        __syncthreads();
    }
    uint32_t inc = sbuf[t], excl = inc - tsum[t];
    if (excl < k && inc >= k) {          // unique crossing thread
        uint32_t cum = excl;
        for (int bin = t * 4 + 3; bin >= t * 4; bin--) {
            uint32_t hh = hist[0][bin];
            if (cum + hh >= k) {
                T_sh = bin; binT[bl] = bin; rrem[bl] = (int)(k - cum);
                break;
            }
            cum += hh;
        }
    }
    __syncthreads();
    int T = T_sh;

    // phase 3: compact (wave-aggregated appends to private counters)
    int lane = t & 63;
    const uint32_t* kp = keys32 + (size_t)b * NTOT + off;
    uint32_t kbase = (uint32_t)(b * KTOT + l * 2000);
    for (int i0 = 0; i0 < seg; i0 += 1024) {
        int i = i0 + t;
        bool in = i < seg;
        uint32_t u = in ? kp[i] : 0u;
        int bin = (int)(u >> 20);
        bool pk = in && (bin > T);
        unsigned long long mk = __ballot(pk);
        if (mk) {
            int leader = __ffsll(mk) - 1;
            uint32_t bs = 0;
            if (lane == leader) bs = atomicAdd(&keep_cnt[bl], (uint32_t)__popcll(mk));
            bs = __shfl(bs, leader, 64);
            if (pk) {
                int pos = __popcll(mk & ((1ull << lane) - 1ull));
                keep[kbase + bs + (uint32_t)pos] = (uint32_t)(off + i);
            }
        }
        bool pc = in && (bin == T);
        unsigned long long mc = __ballot(pc);
        if (mc) {
            int leader = __ffsll(mc) - 1;
            uint32_t bs = 0;
            if (lane == leader) bs = atomicAdd(&cand_cnt[bl], (uint32_t)__popcll(mc));
            bs = __shfl(bs, leader, 64);
            if (pc) {
                int pos = __popcll(mc & ((1ull << lane) - 1ull));
                uint32_t p = bs + (uint32_t)pos;
                if (p < CAP) cand[(size_t)bl * CAP + p] = (uint32_t)(off + i);
            }
        }
    }
}

// ---- kernel 2: exact radix select over candidates, append top-r ----
__global__ void k_select(const uint32_t* __restrict__ keys32, const uint32_t* __restrict__ cand,
                         const uint32_t* __restrict__ cand_cnt, const int* __restrict__ rrem,
                         uint32_t* __restrict__ keep, uint32_t* __restrict__ keep_cnt) {
    int bl = blockIdx.x;             // 40 blocks
    int b = bl / 5, l = bl % 5;
    int C = (int)min(cand_cnt[bl], (uint32_t)CAP);
    int r = rrem[bl];
    const uint32_t* cd = cand + (size_t)bl * CAP;
    __shared__ uint32_t sh_hist[256];
    __shared__ unsigned long long pref_sh;
    __shared__ int kk_sh;
    int t = threadIdx.x;             // 256 threads
    if (t == 0) { pref_sh = 0ull; kk_sh = r; }
    __syncthreads();
    for (int shift = 56; shift >= 0; shift -= 8) {
        sh_hist[t] = 0u;
        __syncthreads();
        unsigned long long pref = pref_sh;
        for (int i = t; i < C; i += 256) {
            uint32_t n = cd[i];
            unsigned long long key =
                ((unsigned long long)keys32[(size_t)b * NTOT + n] << 32) | (uint32_t)(~n);
            bool match = (shift == 56) || ((key >> (shift + 8)) == (pref >> (shift + 8)));
            if (match) atomicAdd(&sh_hist[(uint32_t)(key >> shift) & 255u], 1u);
        }
        __syncthreads();
        if (t == 0) {
            int kk = kk_sh; uint32_t cum = 0;
            for (int d = 255; d >= 0; d--) {
                uint32_t hh = sh_hist[d];
                if (cum + hh >= (uint32_t)kk) {
                    pref_sh = pref | ((unsigned long long)d << shift);
                    kk_sh = kk - (int)cum;
                    break;
                }
                cum += hh;
            }
        }
        __syncthreads();
    }
    unsigned long long Tk = pref_sh;
    int lane = t & 63;
    for (int i0 = 0; i0 < C; i0 += 256) {
        int i = i0 + t;
        bool in = i < C;
        uint32_t n = in ? cd[i] : 0u;
        unsigned long long key = in ?
            (((unsigned long long)keys32[(size_t)b * NTOT + n] << 32) | (uint32_t)(~n)) : 0ull;
        bool pr = in && (key >= Tk);
        unsigned long long mk = __ballot(pr);
        if (mk) {
            int leader = __ffsll(mk) - 1;
            uint32_t bs = 0;
            if (lane == leader) bs = atomicAdd(&keep_cnt[bl], (uint32_t)__popcll(mk));
            bs = __shfl(bs, leader, 64);
            if (pr) {
                int pos = __popcll(mk & ((1ull << lane) - 1ull));
                keep[(size_t)b * KTOT + l * 2000 + bs + (uint32_t)pos] = n;
            }
        }
    }
}

// ---- kernel 3: decode + clip + validity for kept anchors ----
__global__ void k_decode(const float* __restrict__ b0, const float* __restrict__ b1,
                         const float* __restrict__ b2, const float* __restrict__ b3,
                         const float* __restrict__ b4, const float* __restrict__ anchors,
                         const uint32_t* __restrict__ keys32, const uint32_t* __restrict__ keep,
                         float4* __restrict__ nbox, unsigned long long* __restrict__ nkey,
                         float* __restrict__ nscore) {
    int gid = blockIdx.x * blockDim.x + threadIdx.x;
    if (gid >= BATCH * KTOT) return;
    int b = gid / KTOT;
    int n = (int)keep[gid];
    int l, H, W, loc; locate(n, l, H, W, loc);
    int a = loc % 3, hw = loc / 3;
    int w = hw % W, h = hw / W;
    const float* bp = (l == 0) ? b0 : (l == 1) ? b1 : (l == 2) ? b2 : (l == 3) ? b3 : b4;
    int HW = H * W;
    int base = ((b * 12 + a * 4) * H + h) * W + w;
    float dx = bp[base], dy = bp[base + HW];
    float dw = bp[base + 2 * HW], dh = bp[base + 3 * HW];
    float ax1 = anchors[4 * n], ay1 = anchors[4 * n + 1];
    float ax2 = anchors[4 * n + 2], ay2 = anchors[4 * n + 3];
    float wa = ax2 - ax1, ha = ay2 - ay1;
    float cxa = ax1 + 0.5f * wa, cya = ay1 + 0.5f * ha;
    const float CLIPV = 4.135166556742356f;    // log(1000/16)
    dw = fminf(dw, CLIPV); dh = fminf(dh, CLIPV);
    float cx = dx * wa + cxa, cy = dy * ha + cya;
    float pw = expf(dw) * wa, ph = expf(dh) * ha;
    float x1 = cx - 0.5f * pw, y1 = cy - 0.5f * ph;
    float x2 = cx + 0.5f * pw, y2 = cy + 0.5f * ph;
    x1 = fminf(fmaxf(x1, 0.f), 1216.f); x2 = fminf(fmaxf(x2, 0.f), 1216.f);
    y1 = fminf(fmaxf(y1, 0.f), 800.f);  y2 = fminf(fmaxf(y2, 0.f), 800.f);
    bool valid = ((x2 - x1) >= 1e-3f) && ((y2 - y1) >= 1e-3f);
    uint32_t o = keys32[(size_t)b * NTOT + n];
    uint32_t sb = (o & 0x80000000u) ? (o ^ 0x80000000u) : ~o;
    float score = __uint_as_float(sb);
    float off = (float)l * 1217.0f;            // max(IMG_H,IMG_W)+1
    nbox[gid] = make_float4(x1 + off, y1 + off, x2 + off, y2 + off);
    nkey[gid] = valid ? (((unsigned long long)o << 32) | (uint32_t)(~n)) : 0ull;
    nscore[gid] = score;
}

// ---- kernel 4: greedy batched NMS, one block per batch image ----
__launch_bounds__(1024)
__global__ void k_nms(const float4* __restrict__ nbox, const unsigned long long* __restrict__ nkey,
                      const float* __restrict__ nscore, float* __restrict__ out) {
    int b = blockIdx.x, t = threadIdx.x;
    float4 bx[9]; unsigned long long key[9]; float sc[9];
#pragma unroll
    for (int i = 0; i < 9; i++) {
        int j = t + i * 1024;
        if (j < KTOT) {
            bx[i] = nbox[b * KTOT + j];
            key[i] = nkey[b * KTOT + j];
            sc[i] = nscore[b * KTOT + j];
        } else {
            bx[i] = make_float4(0.f, 0.f, 0.f, 0.f);
            key[i] = 0ull; sc[i] = 0.f;
        }
    }
    __shared__ unsigned long long wred[16];
    __shared__ unsigned long long gk_sh;
    __shared__ float pick[5];
    int lane = t & 63, wid = t >> 6;
    for (int it = 0; it < 100; it++) {
        unsigned long long lm = 0ull;
#pragma unroll
        for (int i = 0; i < 9; i++) lm = (key[i] > lm) ? key[i] : lm;
#pragma unroll
        for (int o = 32; o > 0; o >>= 1) {
            unsigned long long other = __shfl_down(lm, o, 64);
            lm = (other > lm) ? other : lm;
        }
        if (lane == 0) wred[wid] = lm;
        __syncthreads();
        if (t == 0) {
            unsigned long long m = wred[0];
            for (int q = 1; q < 16; q++) m = (wred[q] > m) ? wred[q] : m;
            gk_sh = m;
        }
        __syncthreads();
        unsigned long long g = gk_sh;
        if (g == 0ull) break;   // uniform exit
#pragma unroll
        for (int i = 0; i < 9; i++) {
            if (key[i] == g) {  // unique owner (keys embed unique anchor idx)
                uint32_t n = ~(uint32_t)(g & 0xFFFFFFFFull);
                float off = (float)level_of((int)n) * 1217.0f;
                float* ob = out + ((size_t)b * 100 + it) * 4;
                ob[0] = bx[i].x - off; ob[1] = bx[i].y - off;
                ob[2] = bx[i].z - off; ob[3] = bx[i].w - off;
                out[3200 + b * 100 + it] = sc[i];
                pick[0] = bx[i].x; pick[1] = bx[i].y;
                pick[2] = bx[i].z; pick[3] = bx[i].w;
                pick[4] = (bx[i].z - bx[i].x) * (bx[i].w - bx[i].y);
                key[i] = 0ull;  // suppress self
            }
        }
        __syncthreads();
        float px1 = pick[0], py1 = pick[1], px2 = pick[2], py2 = pick[3], pa = pick[4];
#pragma unroll
        for (int i = 0; i < 9; i++) {
            if (key[i] != 0ull) {
                float xx1 = fmaxf(bx[i].x, px1), yy1 = fmaxf(bx[i].y, py1);
                float xx2 = fminf(bx[i].z, px2), yy2 = fminf(bx[i].w, py2);
                float inter = fmaxf(xx2 - xx1, 0.f) * fmaxf(yy2 - yy1, 0.f);
                float aj = (bx[i].z - bx[i].x) * (bx[i].w - bx[i].y);
                float un = aj + pa - inter;
                float iou = (un > 0.f) ? (inter / un) : 0.f;
                if (iou > 0.7f) key[i] = 0ull;
            }
        }
        __syncthreads();
    }
}

extern "C" void kernel_launch(void* const* d_in, const int* in_sizes, int n_in,
                              void* d_out, int out_size, void* d_ws, size_t ws_size,
                              hipStream_t stream) {
    // setup_inputs() dict order: cls0, box0, cls1, box1, cls2, box2, cls3, box3, cls4, box4, anchors
    const float* cls[5] = { (const float*)d_in[0], (const float*)d_in[2], (const float*)d_in[4],
                            (const float*)d_in[6], (const float*)d_in[8] };
    const float* box[5] = { (const float*)d_in[1], (const float*)d_in[3], (const float*)d_in[5],
                            (const float*)d_in[7], (const float*)d_in[9] };
    const float* anchors = (const float*)d_in[10];
    float* out = (float*)d_out;

    // workspace layout
    uint32_t* keys32   = (uint32_t*)d_ws;                      // B*NTOT
    int*      binT     = (int*)(keys32 + (size_t)BATCH * NTOT);// 40
    int*      rrem     = binT + 40;                            // 40
    uint32_t* keep_cnt = (uint32_t*)(rrem + 40);               // 40
    uint32_t* cand_cnt = keep_cnt + 40;                        // 40
    uint32_t* keep     = cand_cnt + 40;                        // B*KTOT
    uint32_t* cand     = keep + (size_t)BATCH * KTOT;          // 40*CAP
    size_t u32s = (size_t)BATCH * NTOT + 160 + (size_t)BATCH * KTOT + (size_t)40 * CAP;
    u32s = (u32s + 3) & ~(size_t)3;
    float4* nbox = (float4*)((uint32_t*)d_ws + u32s);          // B*KTOT
    unsigned long long* nkey = (unsigned long long*)(nbox + (size_t)BATCH * KTOT);
    float* nscore = (float*)(nkey + (size_t)BATCH * KTOT);

    k_zero<<<4, 1024, 0, stream>>>(keep_cnt, out, out_size);
    k_topk<<<40, 1024, 0, stream>>>(cls[0], cls[1], cls[2], cls[3], cls[4],
                                    keys32, keep, keep_cnt, cand, cand_cnt, binT, rrem);
    k_select<<<40, 256, 0, stream>>>(keys32, cand, cand_cnt, rrem, keep, keep_cnt);
    {
        int tot = BATCH * KTOT;
        k_decode<<<(tot + 255) / 256, 256, 0, stream>>>(box[0], box[1], box[2], box[3], box[4],
                                                        anchors, keys32, keep, nbox, nkey, nscore);
    }
    k_nms<<<BATCH, 1024, 0, stream>>>(nbox, nkey, nscore, out);
}

// Round 3
// 331.178 us; speedup vs baseline: 4.5423x; 1.8789x over previous
//
#include <hip/hip_runtime.h>
#include <cstdint>

#define NTOT 242991
#define BATCH 8
#define KTOT 8741           // 2000*4 + 741
#define CAP 8192            // candidate buffer per (b,level)
#define NBIN 4096           // histogram bins (top 12 ordered bits)
#define CSTR 16             // counter padding stride (64 B / cache-line isolation)
#define MEMTOT 1943928      // sum over levels of B*3*H*W
#define ANCTOT (BATCH * NTOT)

__device__ __forceinline__ int level_of(int n) {
    if (n < 182400) return 0;
    if (n < 228000) return 1;
    if (n < 239400) return 2;
    if (n < 242250) return 3;
    return 4;
}

__device__ __forceinline__ void locate(int n, int& l, int& H, int& W, int& loc) {
    if (n < 182400)      { l = 0; H = 200; W = 304; loc = n; }
    else if (n < 228000) { l = 1; H = 100; W = 152; loc = n - 182400; }
    else if (n < 239400) { l = 2; H = 50;  W = 76;  loc = n - 228000; }
    else if (n < 242250) { l = 3; H = 25;  W = 38;  loc = n - 239400; }
    else                 { l = 4; H = 13;  W = 19;  loc = n - 242250; }
}

// classify mem-flat cls index -> bl = b*5+l
__device__ __forceinline__ int classify_bl(int x) {
    int l, HW;
    if (x < 1459200)      { l = 0; HW = 60800; }
    else if (x < 1824000) { l = 1; HW = 15200; x -= 1459200; }
    else if (x < 1915200) { l = 2; HW = 3800;  x -= 1824000; }
    else if (x < 1938000) { l = 3; HW = 950;   x -= 1915200; }
    else                  { l = 4; HW = 247;   x -= 1938000; }
    return (x / (3 * HW)) * 5 + l;
}

// ---- kernel 0: zero meta blob + output ----
__global__ void k_zero(uint32_t* meta, int meta_n, float* out, int out_n) {
    int i = blockIdx.x * blockDim.x + threadIdx.x;
    if (i < meta_n) meta[i] = 0u;
    if (i < out_n) out[i] = 0.0f;
}

// ---- kernel 1: scores -> ordered keys (anchor order) + per-(b,l) hist ----
__global__ __launch_bounds__(1024)
void k_keys(const float* __restrict__ c0, const float* __restrict__ c1,
            const float* __restrict__ c2, const float* __restrict__ c3,
            const float* __restrict__ c4,
            uint32_t* __restrict__ keys32, uint32_t* __restrict__ hist) {
    int t = threadIdx.x;
    int base = blockIdx.x * 1024;
    int gid = base + t;
    bool in = gid < MEMTOT;
    __shared__ uint32_t lh[NBIN];

    int bl = 0;
    uint32_t u = 0;
    if (in) {
        int x = gid;
        const float* cp; int HW, off, l;
        if (x < 1459200)      { l = 0; cp = c0; HW = 60800; off = 0; }
        else if (x < 1824000) { l = 1; cp = c1; HW = 15200; off = 182400; x -= 1459200; }
        else if (x < 1915200) { l = 2; cp = c2; HW = 3800;  off = 228000; x -= 1824000; }
        else if (x < 1938000) { l = 3; cp = c3; HW = 950;   off = 239400; x -= 1915200; }
        else                  { l = 4; cp = c4; HW = 247;   off = 242250; x -= 1938000; }
        int seg = 3 * HW;
        int b = x / seg, r = x - b * seg;
        int a = r / HW, pix = r - a * HW;
        int n = off + pix * 3 + a;
        float s = cp[x];
        u = __float_as_uint(s);
        u ^= (u >> 31) ? 0xFFFFFFFFu : 0x80000000u;    // monotonic float->uint
        keys32[(size_t)b * NTOT + n] = u;
        bl = b * 5 + l;
    }
    int blf = classify_bl(base);
    int bll = classify_bl(min(base + 1023, MEMTOT - 1));
    if (blf == bll) {
        for (int j = t; j < NBIN; j += 1024) lh[j] = 0u;
        __syncthreads();
        if (in) atomicAdd(&lh[u >> 20], 1u);
        __syncthreads();
        uint32_t* gh = hist + (size_t)blf * NBIN;
        for (int j = t; j < NBIN; j += 1024) {
            uint32_t v = lh[j];
            if (v) atomicAdd(&gh[j], v);
        }
    } else {
        if (in) atomicAdd(&hist[(size_t)bl * NBIN + (u >> 20)], 1u);
    }
}

// ---- kernel 2: per-(b,l) threshold bin + remainder ----
__global__ void k_bins(const uint32_t* __restrict__ hist, int* __restrict__ binT,
                       int* __restrict__ rrem) {
    int bl = blockIdx.x;             // 40 blocks
    const uint32_t* h = hist + (size_t)bl * NBIN;
    int l = bl % 5;
    uint32_t k = (l == 4) ? 741u : 2000u;
    __shared__ uint32_t tsum[256];
    __shared__ uint32_t cft[256];
    int t = threadIdx.x;             // 256 threads, 16 bins each
    uint32_t s = 0;
    for (int i = 0; i < 16; i++) s += h[t * 16 + i];
    tsum[t] = s;
    __syncthreads();
    if (t == 0) {
        uint32_t c = 0;
        for (int q = 255; q >= 0; q--) { cft[q] = c; c += tsum[q]; }
    }
    __syncthreads();
    if (cft[t] < k && cft[t] + tsum[t] >= k) {
        uint32_t cum = cft[t];
        for (int bin = t * 16 + 15; bin >= t * 16; bin--) {
            uint32_t hh = h[bin];
            if (cum + hh >= k) { binT[bl] = bin; rrem[bl] = (int)(k - cum); break; }
            cum += hh;
        }
    }
}

// ---- kernel 3: wide compact (wave-aggregated, uniformity-checked) ----
__global__ __launch_bounds__(1024)
void k_compact(const uint32_t* __restrict__ keys32, const int* __restrict__ binT,
               uint32_t* __restrict__ keep, uint32_t* __restrict__ keep_cnt,
               uint32_t* __restrict__ cand, uint32_t* __restrict__ cand_cnt) {
    int gid = blockIdx.x * 1024 + threadIdx.x;
    bool in = gid < ANCTOT;
    int b = 0, n = 0, l = 0;
    uint32_t u = 0;
    if (in) {
        b = gid / NTOT; n = gid - b * NTOT;
        l = level_of(n);
        u = keys32[gid];
    }
    int bl = b * 5 + l;
    int T = in ? binT[bl] : 0x7FFFFFFF;
    int bin = (int)(u >> 20);
    bool pk = in && (bin > T);
    bool pc = in && (bin == T);
    int lane = threadIdx.x & 63;

    unsigned long long act = __ballot(in);
    if (act == 0ull) return;
    int lead = __ffsll(act) - 1;
    int bl0 = __shfl(bl, lead, 64);
    bool unif = (__ballot(in && (bl == bl0)) == act);
    if (unif) {
        int b0 = bl0 / 5, l0 = bl0 % 5;
        uint32_t kbase = (uint32_t)(b0 * KTOT + l0 * 2000);
        unsigned long long mk = __ballot(pk);
        if (mk) {
            int leader = __ffsll(mk) - 1;
            uint32_t bs = 0;
            if (lane == leader) bs = atomicAdd(&keep_cnt[bl0 * CSTR], (uint32_t)__popcll(mk));
            bs = __shfl(bs, leader, 64);
            if (pk) {
                int pos = __popcll(mk & ((1ull << lane) - 1ull));
                keep[kbase + bs + (uint32_t)pos] = (uint32_t)n;
            }
        }
        unsigned long long mc = __ballot(pc);
        if (mc) {
            int leader = __ffsll(mc) - 1;
            uint32_t bs = 0;
            if (lane == leader) bs = atomicAdd(&cand_cnt[bl0 * CSTR], (uint32_t)__popcll(mc));
            bs = __shfl(bs, leader, 64);
            if (pc) {
                int pos = __popcll(mc & ((1ull << lane) - 1ull));
                uint32_t p = bs + (uint32_t)pos;
                if (p < CAP) cand[(size_t)bl0 * CAP + p] = (uint32_t)n;
            }
        }
    } else {  // rare straddle waves: scalar atomics
        if (pk) {
            uint32_t p = atomicAdd(&keep_cnt[bl * CSTR], 1u);
            keep[b * KTOT + l * 2000 + p] = (uint32_t)n;
        }
        if (pc) {
            uint32_t p = atomicAdd(&cand_cnt[bl * CSTR], 1u);
            if (p < CAP) cand[(size_t)bl * CAP + p] = (uint32_t)n;
        }
    }
}

// ---- kernel 4: exact radix select over boundary candidates ----
__global__ void k_select(const uint32_t* __restrict__ keys32, const uint32_t* __restrict__ cand,
                         const uint32_t* __restrict__ cand_cnt, const int* __restrict__ rrem,
                         uint32_t* __restrict__ keep, uint32_t* __restrict__ keep_cnt) {
    int bl = blockIdx.x;             // 40 blocks
    int b = bl / 5, l = bl % 5;
    int C = (int)min(cand_cnt[bl * CSTR], (uint32_t)CAP);
    int r = rrem[bl];
    const uint32_t* cd = cand + (size_t)bl * CAP;
    __shared__ uint32_t sh_hist[256];
    __shared__ unsigned long long pref_sh;
    __shared__ int kk_sh;
    int t = threadIdx.x;             // 256 threads
    if (t == 0) { pref_sh = 0ull; kk_sh = r; }
    __syncthreads();
    for (int shift = 56; shift >= 0; shift -= 8) {
        sh_hist[t] = 0u;
        __syncthreads();
        unsigned long long pref = pref_sh;
        for (int i = t; i < C; i += 256) {
            uint32_t n = cd[i];
            unsigned long long key =
                ((unsigned long long)keys32[(size_t)b * NTOT + n] << 32) | (uint32_t)(~n);
            bool match = (shift == 56) || ((key >> (shift + 8)) == (pref >> (shift + 8)));
            if (match) atomicAdd(&sh_hist[(uint32_t)(key >> shift) & 255u], 1u);
        }
        __syncthreads();
        if (t == 0) {
            int kk = kk_sh; uint32_t cum = 0;
            for (int d = 255; d >= 0; d--) {
                uint32_t hh = sh_hist[d];
                if (cum + hh >= (uint32_t)kk) {
                    pref_sh = pref | ((unsigned long long)d << shift);
                    kk_sh = kk - (int)cum;
                    break;
                }
                cum += hh;
            }
        }
        __syncthreads();
    }
    unsigned long long Tk = pref_sh;
    int lane = t & 63;
    for (int i0 = 0; i0 < C; i0 += 256) {
        int i = i0 + t;
        bool in = i < C;
        uint32_t n = in ? cd[i] : 0u;
        unsigned long long key = in ?
            (((unsigned long long)keys32[(size_t)b * NTOT + n] << 32) | (uint32_t)(~n)) : 0ull;
        bool pr = in && (key >= Tk);
        unsigned long long mk = __ballot(pr);
        if (mk) {
            int leader = __ffsll(mk) - 1;
            uint32_t bs = 0;
            if (lane == leader) bs = atomicAdd(&keep_cnt[bl * CSTR], (uint32_t)__popcll(mk));
            bs = __shfl(bs, leader, 64);
            if (pr) {
                int pos = __popcll(mk & ((1ull << lane) - 1ull));
                keep[(size_t)b * KTOT + l * 2000 + bs + (uint32_t)pos] = n;
            }
        }
    }
}

// ---- kernel 5: decode + clip + validity + bucket histogram ----
__global__ void k_decode(const float* __restrict__ b0, const float* __restrict__ b1,
                         const float* __restrict__ b2, const float* __restrict__ b3,
                         const float* __restrict__ b4, const float* __restrict__ anchors,
                         const uint32_t* __restrict__ keys32, const uint32_t* __restrict__ keep,
                         float4* __restrict__ nbox, unsigned long long* __restrict__ nkey,
                         uint32_t* __restrict__ shist) {
    int gid = blockIdx.x * blockDim.x + threadIdx.x;
    if (gid >= BATCH * KTOT) return;
    int b = gid / KTOT;
    int n = (int)keep[gid];
    int l, H, W, loc; locate(n, l, H, W, loc);
    int a = loc % 3, hw = loc / 3;
    int w = hw % W, h = hw / W;
    const float* bp = (l == 0) ? b0 : (l == 1) ? b1 : (l == 2) ? b2 : (l == 3) ? b3 : b4;
    int HW = H * W;
    int base = ((b * 12 + a * 4) * H + h) * W + w;
    float dx = bp[base], dy = bp[base + HW];
    float dw = bp[base + 2 * HW], dh = bp[base + 3 * HW];
    float ax1 = anchors[4 * n], ay1 = anchors[4 * n + 1];
    float ax2 = anchors[4 * n + 2], ay2 = anchors[4 * n + 3];
    float wa = ax2 - ax1, ha = ay2 - ay1;
    float cxa = ax1 + 0.5f * wa, cya = ay1 + 0.5f * ha;
    const float CLIPV = 4.135166556742356f;    // log(1000/16)
    dw = fminf(dw, CLIPV); dh = fminf(dh, CLIPV);
    float cx = dx * wa + cxa, cy = dy * ha + cya;
    float pw = expf(dw) * wa, ph = expf(dh) * ha;
    float x1 = cx - 0.5f * pw, y1 = cy - 0.5f * ph;
    float x2 = cx + 0.5f * pw, y2 = cy + 0.5f * ph;
    x1 = fminf(fmaxf(x1, 0.f), 1216.f); x2 = fminf(fmaxf(x2, 0.f), 1216.f);
    y1 = fminf(fmaxf(y1, 0.f), 800.f);  y2 = fminf(fmaxf(y2, 0.f), 800.f);
    bool valid = ((x2 - x1) >= 1e-3f) && ((y2 - y1) >= 1e-3f);
    uint32_t o = keys32[(size_t)b * NTOT + n];
    float off = (float)l * 1217.0f;            // max(IMG_H,IMG_W)+1
    nbox[gid] = make_float4(x1 + off, y1 + off, x2 + off, y2 + off);
    nkey[gid] = valid ? (((unsigned long long)o << 32) | (uint32_t)(~n)) : 0ull;
    if (valid) atomicAdd(&shist[b * NBIN + (o >> 20)], 1u);
}

// ---- kernel 6: per-image bucket suffix scan -> starts + nonempty list ----
__global__ __launch_bounds__(1024)
void k_scanbuckets(const uint32_t* __restrict__ shist,
                   uint32_t* __restrict__ sstart, uint32_t* __restrict__ scursor,
                   uint32_t* __restrict__ nb_list, uint32_t* __restrict__ nb_cnt) {
    int b = blockIdx.x, t = threadIdx.x;
    const uint32_t* h = shist + (size_t)b * NBIN;
    __shared__ unsigned long long sbuf[1024];
    uint32_t c0 = h[4 * t], c1 = h[4 * t + 1], c2 = h[4 * t + 2], c3 = h[4 * t + 3];
#define PK(c) ((unsigned long long)(c) | ((unsigned long long)((c) > 0u) << 32))
    unsigned long long gsum = PK(c0) + PK(c1) + PK(c2) + PK(c3);
    sbuf[t] = gsum;
    __syncthreads();
    for (int d = 1; d < 1024; d <<= 1) {
        unsigned long long add = (t + d < 1024) ? sbuf[t + d] : 0ull;
        __syncthreads();
        sbuf[t] += add;
        __syncthreads();
    }
    unsigned long long acc = sbuf[t] - gsum;   // suffix strictly above this group
    uint32_t* ss = sstart + (size_t)b * NBIN;
    uint32_t* sc = scursor + (size_t)b * NBIN;
    uint32_t* nl = nb_list + (size_t)b * NBIN;
#define EMIT(q, cq) { int bin = 4 * t + (q); uint32_t st = (uint32_t)acc;            \
                      uint32_t fp = (uint32_t)(acc >> 32);                           \
                      ss[bin] = st; sc[bin] = st;                                    \
                      if (cq) nl[fp] = (uint32_t)bin; acc += PK(cq); }
    EMIT(3, c3) EMIT(2, c2) EMIT(1, c1) EMIT(0, c0)
#undef EMIT
#undef PK
    if (t == 0) nb_cnt[b] = (uint32_t)(sbuf[0] >> 32);
}

// ---- kernel 7: scatter valid keys/boxes into bucket-ordered arrays ----
__global__ void k_scatter(const unsigned long long* __restrict__ nkey,
                          const float4* __restrict__ nbox,
                          uint32_t* __restrict__ scursor,
                          unsigned long long* __restrict__ skey, float4* __restrict__ sbox) {
    int gid = blockIdx.x * blockDim.x + threadIdx.x;
    if (gid >= BATCH * KTOT) return;
    unsigned long long kk = nkey[gid];
    if (kk == 0ull) return;
    int b = gid / KTOT;
    uint32_t bucket = (uint32_t)(kk >> 52);
    uint32_t p = atomicAdd(&scursor[b * NBIN + bucket], 1u);
    skey[(size_t)b * KTOT + p] = kk;
    sbox[(size_t)b * KTOT + p] = nbox[gid];
}

// ---- kernel 8: single-wave sorted-scan NMS per image ----
__global__ __launch_bounds__(64)
void k_scan(const unsigned long long* __restrict__ skey, const float4* __restrict__ sbox,
            const uint32_t* __restrict__ shist, const uint32_t* __restrict__ sstart,
            const uint32_t* __restrict__ nb_list, const uint32_t* __restrict__ nb_cnt,
            float* __restrict__ out) {
    int b = blockIdx.x, lane = threadIdx.x;
    const unsigned long long* K = skey + (size_t)b * KTOT;
    const float4* BX = sbox + (size_t)b * KTOT;
    __shared__ unsigned long long lds_k[4096];   // 32 KB bucket key cache
    float4 s0v = make_float4(0.f, 0.f, 0.f, 0.f), s1v = s0v;
    float a0 = 0.f, a1 = 0.f;
    int cnt = 0;
    int nb = (int)nb_cnt[b];
    for (int e = 0; e < nb && cnt < 100; e++) {
        int q = (int)nb_list[b * NBIN + e];      // buckets in descending key order
        int s = (int)sstart[b * NBIN + q];
        int c = (int)shist[b * NBIN + q];
        bool cached = (c <= 4096);
        if (cached) {
            for (int i = lane; i < c; i += 64) lds_k[i] = K[s + i];
            __syncthreads();
        }
        unsigned long long last = 0ull;
        for (int ext = 0; ext < c && cnt < 100; ext++) {
            // exact max-extract: largest key < last (unfiltered on first)
            unsigned long long lbest = 0ull; int lpos = -1;
            for (int i = lane; i < c; i += 64) {
                unsigned long long kk = cached ? lds_k[i] : K[s + i];
                if ((ext == 0 || kk < last) && kk > lbest) { lbest = kk; lpos = i; }
            }
            unsigned long long m = lbest;
#pragma unroll
            for (int o = 32; o > 0; o >>= 1) {
                unsigned long long oth = __shfl_down(m, o, 64);
                if (oth > m) m = oth;
            }
            m = __shfl(m, 0, 64);
            unsigned long long mk = __ballot(lbest == m && lpos >= 0);
            int owner = __ffsll(mk) - 1;
            int p = __shfl(lpos, owner, 64) + s;
            last = m;
            // candidate test vs selected list (lane i holds selected i / i+64)
            float4 cb = BX[p];
            float ca = (cb.z - cb.x) * (cb.w - cb.y);
            bool hit = false;
            if (lane < cnt) {
                float xx1 = fmaxf(cb.x, s0v.x), yy1 = fmaxf(cb.y, s0v.y);
                float xx2 = fminf(cb.z, s0v.z), yy2 = fminf(cb.w, s0v.w);
                float inter = fmaxf(xx2 - xx1, 0.f) * fmaxf(yy2 - yy1, 0.f);
                float un = ca + a0 - inter;
                float iou = (un > 0.f) ? inter / un : 0.f;
                hit = iou > 0.7f;
            }
            if (lane + 64 < cnt) {
                float xx1 = fmaxf(cb.x, s1v.x), yy1 = fmaxf(cb.y, s1v.y);
                float xx2 = fminf(cb.z, s1v.z), yy2 = fminf(cb.w, s1v.w);
                float inter = fmaxf(xx2 - xx1, 0.f) * fmaxf(yy2 - yy1, 0.f);
                float un = ca + a1 - inter;
                float iou = (un > 0.f) ? inter / un : 0.f;
                hit = hit || (iou > 0.7f);
            }
            if (__ballot(hit) == 0ull) {
                if (cnt < 64) { if (lane == cnt) { s0v = cb; a0 = ca; } }
                else          { if (lane == cnt - 64) { s1v = cb; a1 = ca; } }
                if (lane == 0) {
                    uint32_t n = ~(uint32_t)(m & 0xFFFFFFFFull);
                    float off = (float)level_of((int)n) * 1217.0f;
                    float* ob = out + ((size_t)b * 100 + cnt) * 4;
                    ob[0] = cb.x - off; ob[1] = cb.y - off;
                    ob[2] = cb.z - off; ob[3] = cb.w - off;
                    uint32_t uu = (uint32_t)(m >> 32);
                    uint32_t sb2 = (uu & 0x80000000u) ? (uu ^ 0x80000000u) : ~uu;
                    out[3200 + b * 100 + cnt] = __uint_as_float(sb2);
                }
                cnt++;
            }
        }
        if (cached) __syncthreads();
    }
}

extern "C" void kernel_launch(void* const* d_in, const int* in_sizes, int n_in,
                              void* d_out, int out_size, void* d_ws, size_t ws_size,
                              hipStream_t stream) {
    // setup_inputs() order: cls0, box0, cls1, box1, cls2, box2, cls3, box3, cls4, box4, anchors
    const float* cls[5] = { (const float*)d_in[0], (const float*)d_in[2], (const float*)d_in[4],
                            (const float*)d_in[6], (const float*)d_in[8] };
    const float* box[5] = { (const float*)d_in[1], (const float*)d_in[3], (const float*)d_in[5],
                            (const float*)d_in[7], (const float*)d_in[9] };
    const float* anchors = (const float*)d_in[10];
    float* out = (float*)d_out;

    // ---- workspace layout (u32 units) ----
    uint32_t* W32 = (uint32_t*)d_ws;
    size_t o = 0;
    uint32_t* hist     = W32 + o; o += (size_t)40 * NBIN;      // 163840
    uint32_t* shist    = W32 + o; o += (size_t)BATCH * NBIN;   // 32768
    uint32_t* keep_cnt = W32 + o; o += 40 * CSTR;              // 640
    uint32_t* cand_cnt = W32 + o; o += 40 * CSTR;              // 640
    int*      binT     = (int*)(W32 + o); o += 64;
    int*      rrem     = (int*)(W32 + o); o += 64;
    uint32_t* nb_cnt   = W32 + o; o += 16;
    size_t zero_n = o;                                         // contiguous zero blob
    uint32_t* sstart   = W32 + o; o += (size_t)BATCH * NBIN;
    uint32_t* scursor  = W32 + o; o += (size_t)BATCH * NBIN;
    uint32_t* nb_list  = W32 + o; o += (size_t)BATCH * NBIN;
    uint32_t* keys32   = W32 + o; o += (size_t)ANCTOT;
    uint32_t* keep     = W32 + o; o += (size_t)BATCH * KTOT;
    uint32_t* cand     = W32 + o; o += (size_t)40 * CAP;
    o = (o + 3) & ~(size_t)3;                                  // 16B align
    float4* nbox = (float4*)(W32 + o); o += (size_t)BATCH * KTOT * 4;
    unsigned long long* nkey = (unsigned long long*)(W32 + o); o += (size_t)BATCH * KTOT * 2;
    float4* sbox = (float4*)(W32 + o); o += (size_t)BATCH * KTOT * 4;
    unsigned long long* skey = (unsigned long long*)(W32 + o); o += (size_t)BATCH * KTOT * 2;

    {
        int tot = (int)zero_n;
        k_zero<<<(tot + 1023) / 1024, 1024, 0, stream>>>(hist, tot, out, out_size);
    }
    k_keys<<<(MEMTOT + 1023) / 1024, 1024, 0, stream>>>(cls[0], cls[1], cls[2], cls[3], cls[4],
                                                        keys32, hist);
    k_bins<<<40, 256, 0, stream>>>(hist, binT, rrem);
    k_compact<<<(ANCTOT + 1023) / 1024, 1024, 0, stream>>>(keys32, binT, keep, keep_cnt,
                                                           cand, cand_cnt);
    k_select<<<40, 256, 0, stream>>>(keys32, cand, cand_cnt, rrem, keep, keep_cnt);
    {
        int tot = BATCH * KTOT;
        k_decode<<<(tot + 255) / 256, 256, 0, stream>>>(box[0], box[1], box[2], box[3], box[4],
                                                        anchors, keys32, keep, nbox, nkey, shist);
    }
    k_scanbuckets<<<BATCH, 1024, 0, stream>>>(shist, sstart, scursor, nb_list, nb_cnt);
    {
        int tot = BATCH * KTOT;
        k_scatter<<<(tot + 255) / 256, 256, 0, stream>>>(nkey, nbox, scursor, skey, sbox);
    }
    k_scan<<<BATCH, 64, 0, stream>>>(skey, sbox, shist, sstart, nb_list, nb_cnt, out);
}

// Round 4
// 217.279 us; speedup vs baseline: 6.9235x; 1.5242x over previous
//
#include <hip/hip_runtime.h>
#include <cstdint>

#define NTOT 242991
#define BATCH 8
#define KTOT 8741           // 2000*4 + 741
#define CAP 8192            // candidate buffer per (b,level)
#define NBIN 4096           // histogram bins (top 12 ordered bits)
#define CSTR 16             // counter padding stride
#define MEMTOT 1943928      // sum over levels of B*3*H*W  (== BATCH*NTOT)
#define ANCTOT (BATCH * NTOT)
#define SCAP 4096           // k_scan chunk capacity

__device__ __forceinline__ int level_of(int n) {
    if (n < 182400) return 0;
    if (n < 228000) return 1;
    if (n < 239400) return 2;
    if (n < 242250) return 3;
    return 4;
}

__device__ __forceinline__ void locate(int n, int& l, int& H, int& W, int& loc) {
    if (n < 182400)      { l = 0; H = 200; W = 304; loc = n; }
    else if (n < 228000) { l = 1; H = 100; W = 152; loc = n - 182400; }
    else if (n < 239400) { l = 2; H = 50;  W = 76;  loc = n - 228000; }
    else if (n < 242250) { l = 3; H = 25;  W = 38;  loc = n - 239400; }
    else                 { l = 4; H = 13;  W = 19;  loc = n - 242250; }
}

// classify mem-flat cls index -> bl = b*5+l
__device__ __forceinline__ int classify_bl(int x) {
    int l, HW;
    if (x < 1459200)      { l = 0; HW = 60800; }
    else if (x < 1824000) { l = 1; HW = 15200; x -= 1459200; }
    else if (x < 1915200) { l = 2; HW = 3800;  x -= 1824000; }
    else if (x < 1938000) { l = 3; HW = 950;   x -= 1915200; }
    else                  { l = 4; HW = 247;   x -= 1938000; }
    return (x / (3 * HW)) * 5 + l;
}

// ---- kernel 1: scores -> ordered keys (anchor order) + per-(b,l) hist ----
__global__ __launch_bounds__(1024)
void k_keys(const float* __restrict__ c0, const float* __restrict__ c1,
            const float* __restrict__ c2, const float* __restrict__ c3,
            const float* __restrict__ c4,
            uint32_t* __restrict__ keys32, uint32_t* __restrict__ hist) {
    int t = threadIdx.x;
    int base = blockIdx.x * 1024;
    int gid = base + t;
    bool in = gid < MEMTOT;
    __shared__ uint32_t lh[NBIN];

    int bl = 0;
    uint32_t u = 0;
    if (in) {
        int x = gid;
        const float* cp; int HW, off, l;
        if (x < 1459200)      { l = 0; cp = c0; HW = 60800; off = 0; }
        else if (x < 1824000) { l = 1; cp = c1; HW = 15200; off = 182400; x -= 1459200; }
        else if (x < 1915200) { l = 2; cp = c2; HW = 3800;  off = 228000; x -= 1824000; }
        else if (x < 1938000) { l = 3; cp = c3; HW = 950;   off = 239400; x -= 1915200; }
        else                  { l = 4; cp = c4; HW = 247;   off = 242250; x -= 1938000; }
        int seg = 3 * HW;
        int b = x / seg, r = x - b * seg;
        int a = r / HW, pix = r - a * HW;
        int n = off + pix * 3 + a;
        float s = cp[gid - (base + t) + gid];   // placeholder avoided below
        (void)s;
        float sv = cp[x];
        u = __float_as_uint(sv);
        u ^= (u >> 31) ? 0xFFFFFFFFu : 0x80000000u;    // monotonic float->uint
        keys32[(size_t)b * NTOT + n] = u;
        bl = b * 5 + l;
    }
    int blf = classify_bl(base);
    int bll = classify_bl(min(base + 1023, MEMTOT - 1));
    if (blf == bll) {
        for (int j = t; j < NBIN; j += 1024) lh[j] = 0u;
        __syncthreads();
        if (in) atomicAdd(&lh[u >> 20], 1u);
        __syncthreads();
        uint32_t* gh = hist + (size_t)blf * NBIN;
        for (int j = t; j < NBIN; j += 1024) {
            uint32_t v = lh[j];
            if (v) atomicAdd(&gh[j], v);
        }
    } else {
        if (in) atomicAdd(&hist[(size_t)bl * NBIN + (u >> 20)], 1u);
    }
}

// ---- kernel 2: per-(b,l) threshold bin + remainder (parallel scan) ----
__global__ void k_bins(const uint32_t* __restrict__ hist, int* __restrict__ binT,
                       int* __restrict__ rrem) {
    int bl = blockIdx.x;             // 40 blocks
    const uint32_t* h = hist + (size_t)bl * NBIN;
    int l = bl % 5;
    uint32_t k = (l == 4) ? 741u : 2000u;
    __shared__ uint32_t ts[256];
    __shared__ uint32_t sb[256];
    int t = threadIdx.x;             // 256 threads, 16 bins each
    uint32_t s = 0;
    for (int i = 0; i < 16; i++) s += h[t * 16 + i];
    ts[t] = s; sb[t] = s;
    __syncthreads();
    for (int d = 1; d < 256; d <<= 1) {
        uint32_t add = (t + d < 256) ? sb[t + d] : 0u;
        __syncthreads();
        sb[t] += add;
        __syncthreads();
    }
    uint32_t inc = sb[t], excl = inc - ts[t];   // suffix strictly above this group
    if (excl < k && inc >= k) {
        uint32_t cum = excl;
        for (int bin = t * 16 + 15; bin >= t * 16; bin--) {
            uint32_t hh = h[bin];
            if (cum + hh >= k) { binT[bl] = bin; rrem[bl] = (int)(k - cum); break; }
            cum += hh;
        }
    }
}

// ---- kernel 3: wide compact (wave-aggregated, uniformity-checked) ----
__global__ __launch_bounds__(1024)
void k_compact(const uint32_t* __restrict__ keys32, const int* __restrict__ binT,
               uint32_t* __restrict__ keep, uint32_t* __restrict__ keep_cnt,
               uint32_t* __restrict__ cand, uint32_t* __restrict__ cand_cnt) {
    int gid = blockIdx.x * 1024 + threadIdx.x;
    bool in = gid < ANCTOT;
    int b = 0, n = 0, l = 0;
    uint32_t u = 0;
    if (in) {
        b = gid / NTOT; n = gid - b * NTOT;
        l = level_of(n);
        u = keys32[gid];
    }
    int bl = b * 5 + l;
    int T = in ? binT[bl] : 0x7FFFFFFF;
    int bin = (int)(u >> 20);
    bool pk = in && (bin > T);
    bool pc = in && (bin == T);
    int lane = threadIdx.x & 63;

    unsigned long long act = __ballot(in);
    if (act == 0ull) return;
    int lead = __ffsll(act) - 1;
    int bl0 = __shfl(bl, lead, 64);
    bool unif = (__ballot(in && (bl == bl0)) == act);
    if (unif) {
        int b0 = bl0 / 5, l0 = bl0 % 5;
        uint32_t kbase = (uint32_t)(b0 * KTOT + l0 * 2000);
        unsigned long long mk = __ballot(pk);
        if (mk) {
            int leader = __ffsll(mk) - 1;
            uint32_t bs = 0;
            if (lane == leader) bs = atomicAdd(&keep_cnt[bl0 * CSTR], (uint32_t)__popcll(mk));
            bs = __shfl(bs, leader, 64);
            if (pk) {
                int pos = __popcll(mk & ((1ull << lane) - 1ull));
                keep[kbase + bs + (uint32_t)pos] = (uint32_t)n;
            }
        }
        unsigned long long mc = __ballot(pc);
        if (mc) {
            int leader = __ffsll(mc) - 1;
            uint32_t bs = 0;
            if (lane == leader) bs = atomicAdd(&cand_cnt[bl0 * CSTR], (uint32_t)__popcll(mc));
            bs = __shfl(bs, leader, 64);
            if (pc) {
                int pos = __popcll(mc & ((1ull << lane) - 1ull));
                uint32_t p = bs + (uint32_t)pos;
                if (p < CAP) cand[(size_t)bl0 * CAP + p] = (uint32_t)n;
            }
        }
    } else {  // rare straddle waves: scalar atomics
        if (pk) {
            uint32_t p = atomicAdd(&keep_cnt[bl * CSTR], 1u);
            keep[b * KTOT + l * 2000 + p] = (uint32_t)n;
        }
        if (pc) {
            uint32_t p = atomicAdd(&cand_cnt[bl * CSTR], 1u);
            if (p < CAP) cand[(size_t)bl * CAP + p] = (uint32_t)n;
        }
    }
}

// ---- kernel 4: exact radix select over boundary candidates (52-bit, 5 passes) ----
__global__ __launch_bounds__(1024)
void k_select(const uint32_t* __restrict__ keys32, const uint32_t* __restrict__ cand,
              const uint32_t* __restrict__ cand_cnt, const int* __restrict__ rrem,
              uint32_t* __restrict__ keep, uint32_t* __restrict__ keep_cnt) {
    int bl = blockIdx.x;             // 40 blocks x 1024 threads
    int b = bl / 5, l = bl % 5;
    int C = (int)min(cand_cnt[bl * CSTR], (uint32_t)CAP);
    int r = rrem[bl];
    const uint32_t* cd = cand + (size_t)bl * CAP;
    const uint32_t* kp = keys32 + (size_t)b * NTOT;
    __shared__ uint32_t hist_l[2048];
    __shared__ uint32_t scn[1024];
    __shared__ unsigned long long pref_sh;
    __shared__ uint32_t kk_sh;
    int t = threadIdx.x;
    if (t == 0) { pref_sh = 0ull; kk_sh = (uint32_t)r; }
    unsigned long long maskAcc = 0ull;
    const int shifts[5] = {41, 30, 19, 8, 0};
    const uint32_t masks[5] = {0x7FFu, 0x7FFu, 0x7FFu, 0x7FFu, 0xFFu};
    __syncthreads();
    for (int p = 0; p < 5; p++) {
        int shift = shifts[p];
        uint32_t msk = masks[p];
        for (int j = t; j < 2048; j += 1024) hist_l[j] = 0u;
        __syncthreads();
        unsigned long long pref = pref_sh;
        uint32_t kk = kk_sh;
        for (int i = t; i < C; i += 1024) {
            uint32_t n = cd[i];
            unsigned long long key =
                ((unsigned long long)kp[n] << 32) | (uint32_t)(~n);
            if ((key & maskAcc) == pref)
                atomicAdd(&hist_l[(uint32_t)(key >> shift) & msk], 1u);
        }
        __syncthreads();
        uint32_t g = hist_l[2 * t] + hist_l[2 * t + 1];
        scn[t] = g;
        __syncthreads();
        for (int d = 1; d < 1024; d <<= 1) {
            uint32_t add = (t + d < 1024) ? scn[t + d] : 0u;
            __syncthreads();
            scn[t] += add;
            __syncthreads();
        }
        uint32_t inc = scn[t], excl = inc - g;
        if (excl < kk && inc >= kk) {       // unique crossing thread
            uint32_t hh1 = hist_l[2 * t + 1];
            uint32_t digit, rem;
            if (excl + hh1 >= kk) { digit = 2 * t + 1; rem = kk - excl; }
            else { digit = 2 * t; rem = kk - (excl + hh1); }
            pref_sh = pref | ((unsigned long long)digit << shift);
            kk_sh = rem;
        }
        __syncthreads();
        maskAcc |= (unsigned long long)msk << shift;
    }
    unsigned long long Tk = pref_sh;
    __syncthreads();
    int lane = t & 63;
    for (int i0 = 0; i0 < C; i0 += 1024) {
        int i = i0 + t;
        bool in = i < C;
        uint32_t n = in ? cd[i] : 0u;
        unsigned long long key = in ?
            (((unsigned long long)kp[n] << 32) | (uint32_t)(~n)) : 0ull;
        bool pr = in && ((key & maskAcc) >= Tk);
        unsigned long long mk = __ballot(pr);
        if (mk) {
            int leader = __ffsll(mk) - 1;
            uint32_t bs = 0;
            if (lane == leader) bs = atomicAdd(&keep_cnt[bl * CSTR], (uint32_t)__popcll(mk));
            bs = __shfl(bs, leader, 64);
            if (pr) {
                int pos = __popcll(mk & ((1ull << lane) - 1ull));
                keep[(size_t)b * KTOT + l * 2000 + bs + (uint32_t)pos] = n;
            }
        }
    }
}

// ---- kernel 5: decode + clip + validity + bucket histogram ----
__global__ void k_decode(const float* __restrict__ b0, const float* __restrict__ b1,
                         const float* __restrict__ b2, const float* __restrict__ b3,
                         const float* __restrict__ b4, const float* __restrict__ anchors,
                         const uint32_t* __restrict__ keys32, const uint32_t* __restrict__ keep,
                         float4* __restrict__ nbox, unsigned long long* __restrict__ nkey,
                         uint32_t* __restrict__ shist) {
    int gid = blockIdx.x * blockDim.x + threadIdx.x;
    if (gid >= BATCH * KTOT) return;
    int b = gid / KTOT;
    int n = (int)keep[gid];
    int l, H, W, loc; locate(n, l, H, W, loc);
    int a = loc % 3, hw = loc / 3;
    int w = hw % W, h = hw / W;
    const float* bp = (l == 0) ? b0 : (l == 1) ? b1 : (l == 2) ? b2 : (l == 3) ? b3 : b4;
    int HW = H * W;
    int base = ((b * 12 + a * 4) * H + h) * W + w;
    float dx = bp[base], dy = bp[base + HW];
    float dw = bp[base + 2 * HW], dh = bp[base + 3 * HW];
    float ax1 = anchors[4 * n], ay1 = anchors[4 * n + 1];
    float ax2 = anchors[4 * n + 2], ay2 = anchors[4 * n + 3];
    float wa = ax2 - ax1, ha = ay2 - ay1;
    float cxa = ax1 + 0.5f * wa, cya = ay1 + 0.5f * ha;
    const float CLIPV = 4.135166556742356f;    // log(1000/16)
    dw = fminf(dw, CLIPV); dh = fminf(dh, CLIPV);
    float cx = dx * wa + cxa, cy = dy * ha + cya;
    float pw = expf(dw) * wa, ph = expf(dh) * ha;
    float x1 = cx - 0.5f * pw, y1 = cy - 0.5f * ph;
    float x2 = cx + 0.5f * pw, y2 = cy + 0.5f * ph;
    x1 = fminf(fmaxf(x1, 0.f), 1216.f); x2 = fminf(fmaxf(x2, 0.f), 1216.f);
    y1 = fminf(fmaxf(y1, 0.f), 800.f);  y2 = fminf(fmaxf(y2, 0.f), 800.f);
    bool valid = ((x2 - x1) >= 1e-3f) && ((y2 - y1) >= 1e-3f);
    uint32_t o = keys32[(size_t)b * NTOT + n];
    float off = (float)l * 1217.0f;            // max(IMG_H,IMG_W)+1
    nbox[gid] = make_float4(x1 + off, y1 + off, x2 + off, y2 + off);
    nkey[gid] = valid ? (((unsigned long long)o << 32) | (uint32_t)(~n)) : 0ull;
    if (valid) atomicAdd(&shist[b * NBIN + (o >> 20)], 1u);
}

// ---- kernel 6: fused chunked sort-scan NMS, one 1024-thread block per image ----
__global__ __launch_bounds__(1024)
void k_scan(const unsigned long long* __restrict__ nkey, const float4* __restrict__ nbox,
            const uint32_t* __restrict__ shist, float* __restrict__ out) {
    int b = blockIdx.x, t = threadIdx.x, lane = t & 63, wid = t >> 6;
    const unsigned long long* K = nkey + (size_t)b * KTOT;
    const float4* BX = nbox + (size_t)b * KTOT;

    __shared__ unsigned long long k_l[SCAP];     // 32 KB keys
    __shared__ unsigned short p_l[SCAP];         // 8 KB payload (keep index)
    __shared__ float4 box_l[1024];               // 16 KB box cache / phase-A hist
    __shared__ unsigned char chunk_of[NBIN];     // 4 KB
    __shared__ uint32_t cnt_sh;
    __shared__ unsigned long long gmax_sh;
    __shared__ uint32_t jpos_sh;
    __shared__ unsigned long long wred[16];

    // ---- phase A: bucket suffix-cumulative -> chunk ids ----
    uint32_t* hist_l = (uint32_t*)box_l;         // 4096 u32
    uint32_t* g_l = (uint32_t*)k_l;              // 1024 u32 scan buffer
    for (int j = t; j < NBIN; j += 1024) hist_l[j] = shist[b * NBIN + j];
    __syncthreads();
    uint32_t h0 = hist_l[4 * t], h1 = hist_l[4 * t + 1],
             h2 = hist_l[4 * t + 2], h3 = hist_l[4 * t + 3];
    uint32_t g = h0 + h1 + h2 + h3;
    g_l[t] = g;
    __syncthreads();
    for (int d = 1; d < 1024; d <<= 1) {
        uint32_t add = (t + d < 1024) ? g_l[t + d] : 0u;
        __syncthreads();
        g_l[t] += add;
        __syncthreads();
    }
    uint32_t acc = g_l[t] - g;                   // suffix strictly above this group
    chunk_of[4 * t + 3] = (unsigned char)min(acc >> 10, 255u); acc += h3;
    chunk_of[4 * t + 2] = (unsigned char)min(acc >> 10, 255u); acc += h2;
    chunk_of[4 * t + 1] = (unsigned char)min(acc >> 10, 255u); acc += h1;
    chunk_of[4 * t + 0] = (unsigned char)min(acc >> 10, 255u);
    __syncthreads();

    // ---- chunk loop ----
    uint32_t picks = 0;                          // block-uniform (replicated)
    float4 sel0 = make_float4(0.f, 0.f, 0.f, 0.f), sel1 = sel0;
    float sa0 = 0.f, sa1 = 0.f;
    for (int m = 0; m <= 8 && picks < 100; m++) {
        if (t == 0) cnt_sh = 0u;
        __syncthreads();
        // gather chunk m (ballot-aggregated LDS append)
        for (int j0 = 0; j0 < KTOT; j0 += 1024) {
            int j = j0 + t;
            unsigned long long kk = 0ull;
            bool take = false;
            if (j < KTOT) {
                kk = K[j];
                take = (kk != 0ull) && (chunk_of[(uint32_t)(kk >> 52)] == (unsigned char)m);
            }
            unsigned long long msk = __ballot(take);
            if (msk) {
                int leader = __ffsll(msk) - 1;
                uint32_t bs = 0;
                if (lane == leader) bs = atomicAdd(&cnt_sh, (uint32_t)__popcll(msk));
                bs = __shfl(bs, leader, 64);
                if (take) {
                    uint32_t pos = bs + (uint32_t)__popcll(msk & ((1ull << lane) - 1ull));
                    if (pos < SCAP) { k_l[pos] = kk; p_l[pos] = (unsigned short)j; }
                }
            }
        }
        __syncthreads();
        uint32_t cnt = cnt_sh;
        if (cnt == 0u) continue;

        if (cnt <= SCAP) {
            // pad to pow2 and bitonic sort descending (key + payload)
            uint32_t P = 128;
            while (P < cnt) P <<= 1;
            for (uint32_t j = cnt + t; j < P; j += 1024) k_l[j] = 0ull;
            __syncthreads();
            for (uint32_t size = 2; size <= P; size <<= 1) {
                for (uint32_t stride = size >> 1; stride > 0; stride >>= 1) {
                    for (uint32_t i = t; i < P; i += 1024) {
                        uint32_t j2 = i ^ stride;
                        if (j2 > i) {
                            unsigned long long a = k_l[i], c = k_l[j2];
                            bool descBlock = ((i & size) == 0);
                            bool sw = descBlock ? (a < c) : (a > c);
                            if (sw) {
                                k_l[i] = c; k_l[j2] = a;
                                unsigned short tp = p_l[i]; p_l[i] = p_l[j2]; p_l[j2] = tp;
                            }
                        }
                    }
                    __syncthreads();
                }
            }
            // prefetch boxes for first 1024 sorted candidates
            uint32_t nbx = min(cnt, 1024u);
            for (uint32_t i = t; i < nbx; i += 1024) box_l[i] = BX[p_l[i]];
            __syncthreads();
            // sorted linear scan (all waves replicate; no syncs inside)
            for (uint32_t i = 0; i < cnt && picks < 100u; i++) {
                unsigned long long mkey = k_l[i];
                float4 cb = (i < nbx) ? box_l[i] : BX[p_l[i]];
                float ca = (cb.z - cb.x) * (cb.w - cb.y);
                bool hit = false;
                if ((uint32_t)lane < picks) {
                    float xx1 = fmaxf(cb.x, sel0.x), yy1 = fmaxf(cb.y, sel0.y);
                    float xx2 = fminf(cb.z, sel0.z), yy2 = fminf(cb.w, sel0.w);
                    float inter = fmaxf(xx2 - xx1, 0.f) * fmaxf(yy2 - yy1, 0.f);
                    float un = ca + sa0 - inter;
                    hit = (un > 0.f) && (inter / un > 0.7f);
                }
                if ((uint32_t)(lane + 64) < picks) {
                    float xx1 = fmaxf(cb.x, sel1.x), yy1 = fmaxf(cb.y, sel1.y);
                    float xx2 = fminf(cb.z, sel1.z), yy2 = fminf(cb.w, sel1.w);
                    float inter = fmaxf(xx2 - xx1, 0.f) * fmaxf(yy2 - yy1, 0.f);
                    float un = ca + sa1 - inter;
                    hit = hit || ((un > 0.f) && (inter / un > 0.7f));
                }
                if (__ballot(hit) == 0ull) {
                    if (picks < 64u) { if ((uint32_t)lane == picks) { sel0 = cb; sa0 = ca; } }
                    else { if ((uint32_t)lane == picks - 64u) { sel1 = cb; sa1 = ca; } }
                    if (t == 0) {
                        uint32_t n = ~(uint32_t)(mkey & 0xFFFFFFFFull);
                        float off = (float)level_of((int)n) * 1217.0f;
                        float* ob = out + ((size_t)b * 100 + picks) * 4;
                        ob[0] = cb.x - off; ob[1] = cb.y - off;
                        ob[2] = cb.z - off; ob[3] = cb.w - off;
                        uint32_t uu = (uint32_t)(mkey >> 32);
                        uint32_t sb2 = (uu & 0x80000000u) ? (uu ^ 0x80000000u) : ~uu;
                        out[3200 + b * 100 + picks] = __uint_as_float(sb2);
                    }
                    picks++;
                }
            }
            __syncthreads();
        } else {
            // exact fallback for oversized chunk: repeated block-wide max-extract
            unsigned long long last = 0ull;
            bool first = true;
            for (uint32_t done = 0; done < cnt && picks < 100u; done++) {
                unsigned long long lbest = 0ull;
                uint32_t jbest = 0;
                for (int j = t; j < KTOT; j += 1024) {
                    unsigned long long kk = K[j];
                    if (kk != 0ull && chunk_of[(uint32_t)(kk >> 52)] == (unsigned char)m &&
                        (first || kk < last) && kk > lbest) { lbest = kk; jbest = (uint32_t)j; }
                }
                unsigned long long wm = lbest;
#pragma unroll
                for (int o2 = 32; o2 > 0; o2 >>= 1) {
                    unsigned long long oth = __shfl_down(wm, o2, 64);
                    if (oth > wm) wm = oth;
                }
                if (lane == 0) wred[wid] = wm;
                __syncthreads();
                if (t == 0) {
                    unsigned long long mm = wred[0];
                    for (int q = 1; q < 16; q++) if (wred[q] > mm) mm = wred[q];
                    gmax_sh = mm;
                }
                __syncthreads();
                unsigned long long gm = gmax_sh;
                if (gm == 0ull) break;
                if (lbest == gm) jpos_sh = jbest;   // unique owner
                __syncthreads();
                float4 cb = BX[jpos_sh];
                float ca = (cb.z - cb.x) * (cb.w - cb.y);
                bool hit = false;
                if ((uint32_t)lane < picks) {
                    float xx1 = fmaxf(cb.x, sel0.x), yy1 = fmaxf(cb.y, sel0.y);
                    float xx2 = fminf(cb.z, sel0.z), yy2 = fminf(cb.w, sel0.w);
                    float inter = fmaxf(xx2 - xx1, 0.f) * fmaxf(yy2 - yy1, 0.f);
                    float un = ca + sa0 - inter;
                    hit = (un > 0.f) && (inter / un > 0.7f);
                }
                if ((uint32_t)(lane + 64) < picks) {
                    float xx1 = fmaxf(cb.x, sel1.x), yy1 = fmaxf(cb.y, sel1.y);
                    float xx2 = fminf(cb.z, sel1.z), yy2 = fminf(cb.w, sel1.w);
                    float inter = fmaxf(xx2 - xx1, 0.f) * fmaxf(yy2 - yy1, 0.f);
                    float un = ca + sa1 - inter;
                    hit = hit || ((un > 0.f) && (inter / un > 0.7f));
                }
                if (__ballot(hit) == 0ull) {
                    if (picks < 64u) { if ((uint32_t)lane == picks) { sel0 = cb; sa0 = ca; } }
                    else { if ((uint32_t)lane == picks - 64u) { sel1 = cb; sa1 = ca; } }
                    if (t == 0) {
                        uint32_t n = ~(uint32_t)(gm & 0xFFFFFFFFull);
                        float off = (float)level_of((int)n) * 1217.0f;
                        float* ob = out + ((size_t)b * 100 + picks) * 4;
                        ob[0] = cb.x - off; ob[1] = cb.y - off;
                        ob[2] = cb.z - off; ob[3] = cb.w - off;
                        uint32_t uu = (uint32_t)(gm >> 32);
                        uint32_t sb2 = (uu & 0x80000000u) ? (uu ^ 0x80000000u) : ~uu;
                        out[3200 + b * 100 + picks] = __uint_as_float(sb2);
                    }
                    picks++;
                }
                last = gm; first = false;
                __syncthreads();
            }
        }
    }
    // zero-fill unselected output slots
    for (uint32_t i = picks + (uint32_t)t; i < 100u; i += 1024u) {
        float* ob = out + ((size_t)b * 100 + i) * 4;
        ob[0] = 0.f; ob[1] = 0.f; ob[2] = 0.f; ob[3] = 0.f;
        out[3200 + b * 100 + i] = 0.f;
    }
}

extern "C" void kernel_launch(void* const* d_in, const int* in_sizes, int n_in,
                              void* d_out, int out_size, void* d_ws, size_t ws_size,
                              hipStream_t stream) {
    // setup_inputs() order: cls0, box0, cls1, box1, cls2, box2, cls3, box3, cls4, box4, anchors
    const float* cls[5] = { (const float*)d_in[0], (const float*)d_in[2], (const float*)d_in[4],
                            (const float*)d_in[6], (const float*)d_in[8] };
    const float* box[5] = { (const float*)d_in[1], (const float*)d_in[3], (const float*)d_in[5],
                            (const float*)d_in[7], (const float*)d_in[9] };
    const float* anchors = (const float*)d_in[10];
    float* out = (float*)d_out;

    // ---- workspace layout (u32 units). Zero blob first (one memset). ----
    uint32_t* W32 = (uint32_t*)d_ws;
    size_t o = 0;
    uint32_t* hist     = W32 + o; o += (size_t)40 * NBIN;      // 163840
    uint32_t* shist    = W32 + o; o += (size_t)BATCH * NBIN;   // 32768
    uint32_t* keep_cnt = W32 + o; o += 40 * CSTR;              // 640
    uint32_t* cand_cnt = W32 + o; o += 40 * CSTR;              // 640
    size_t zero_n = o;
    int*      binT     = (int*)(W32 + o); o += 64;
    int*      rrem     = (int*)(W32 + o); o += 64;
    uint32_t* keys32   = W32 + o; o += (size_t)ANCTOT;
    uint32_t* keep     = W32 + o; o += (size_t)BATCH * KTOT;
    uint32_t* cand     = W32 + o; o += (size_t)40 * CAP;
    o = (o + 3) & ~(size_t)3;                                  // 16B align
    float4* nbox = (float4*)(W32 + o); o += (size_t)BATCH * KTOT * 4;
    unsigned long long* nkey = (unsigned long long*)(W32 + o); o += (size_t)BATCH * KTOT * 2;

    hipMemsetAsync(d_ws, 0, zero_n * sizeof(uint32_t), stream);
    k_keys<<<(MEMTOT + 1023) / 1024, 1024, 0, stream>>>(cls[0], cls[1], cls[2], cls[3], cls[4],
                                                        keys32, hist);
    k_bins<<<40, 256, 0, stream>>>(hist, binT, rrem);
    k_compact<<<(ANCTOT + 1023) / 1024, 1024, 0, stream>>>(keys32, binT, keep, keep_cnt,
                                                           cand, cand_cnt);
    k_select<<<40, 1024, 0, stream>>>(keys32, cand, cand_cnt, rrem, keep, keep_cnt);
    {
        int tot = BATCH * KTOT;
        k_decode<<<(tot + 255) / 256, 256, 0, stream>>>(box[0], box[1], box[2], box[3], box[4],
                                                        anchors, keys32, keep, nbox, nkey, shist);
    }
    k_scan<<<BATCH, 1024, 0, stream>>>(nkey, nbox, shist, out);
}